// Round 1
// baseline (728.287 us; speedup 1.0000x reference)
//
#include <hip/hip_runtime.h>
#include <hip/hip_bf16.h>
#include <math.h>

#define N_NODES 100000
#define N_EDGES 1600000

// ---------------------------------------------------------------------------
// K1: fused Q/K/V projection. Weights staged in LDS (48.75 KB). One wave per
// node (grid-stride): lane l holds x[n,l]; broadcast x_k via __shfl, FMA with
// W[k][l] read from LDS (64 consecutive floats -> 2 lanes/bank, conflict-free).
// ---------------------------------------------------------------------------
__global__ __launch_bounds__(256) void qkv_kernel(
    const float* __restrict__ x,
    const float* __restrict__ Wq, const float* __restrict__ bq,
    const float* __restrict__ Wk, const float* __restrict__ bk,
    const float* __restrict__ Wv, const float* __restrict__ bv,
    float* __restrict__ Q, float* __restrict__ K, float* __restrict__ V)
{
    __shared__ float wq[64 * 64], wk[64 * 64], wv[64 * 64];
    __shared__ float sbq[64], sbk[64], sbv[64];
    int tid = threadIdx.x;
    for (int i = tid; i < 64 * 64; i += 256) {
        wq[i] = Wq[i]; wk[i] = Wk[i]; wv[i] = Wv[i];
    }
    if (tid < 64) { sbq[tid] = bq[tid]; sbk[tid] = bk[tid]; sbv[tid] = bv[tid]; }
    __syncthreads();

    int lane = tid & 63;
    int wid = blockIdx.x * 4 + (tid >> 6);
    int nw = gridDim.x * 4;
    for (int n = wid; n < N_NODES; n += nw) {
        float xv = x[n * 64 + lane];
        float aq = sbq[lane], ak = sbk[lane], av = sbv[lane];
        #pragma unroll
        for (int k = 0; k < 64; ++k) {
            float xk = __shfl(xv, k);
            aq = fmaf(xk, wq[k * 64 + lane], aq);
            ak = fmaf(xk, wk[k * 64 + lane], ak);
            av = fmaf(xk, wv[k * 64 + lane], av);
        }
        Q[n * 64 + lane] = aq;
        K[n * 64 + lane] = ak;
        V[n * 64 + lane] = av;
    }
}

// ---------------------------------------------------------------------------
// CSR build: histogram of source nodes -> exclusive scan -> scatter col ids.
// ---------------------------------------------------------------------------
__global__ void deg_kernel(const int* __restrict__ ei, int* __restrict__ deg)
{
    int e = blockIdx.x * blockDim.x + threadIdx.x;
    if (e < N_EDGES) atomicAdd(&deg[ei[e]], 1);
}

__global__ __launch_bounds__(1024) void scan_kernel(
    const int* __restrict__ deg, int* __restrict__ cur)
{
    __shared__ int part[1024];
    int t = threadIdx.x;
    const int CH = (N_NODES + 1023) / 1024;   // 98 elems / thread
    int lo = t * CH;
    int hi = lo + CH; if (hi > N_NODES) hi = N_NODES;
    int s = 0;
    for (int i = lo; i < hi; ++i) s += deg[i];
    part[t] = s;
    __syncthreads();
    // Hillis-Steele inclusive scan over 1024 partials
    for (int off = 1; off < 1024; off <<= 1) {
        int v = (t >= off) ? part[t - off] : 0;
        __syncthreads();
        part[t] += v;
        __syncthreads();
    }
    int run = part[t] - s;                    // exclusive prefix for this chunk
    for (int i = lo; i < hi; ++i) { cur[i] = run; run += deg[i]; }
}

__global__ void scatter_kernel(const int* __restrict__ ei,
                               int* __restrict__ cur, int* __restrict__ elist)
{
    int e = blockIdx.x * blockDim.x + threadIdx.x;
    if (e < N_EDGES) {
        int r = ei[e];
        int c = ei[N_EDGES + e];
        int pos = atomicAdd(&cur[r], 1);      // cur[r] ends at segment end
        elist[pos] = c;
    }
}

// ---------------------------------------------------------------------------
// K6: per-node online-softmax aggregation. One wave per node; lane l owns
// (head = l>>3, dim = l&7). Per edge: coalesced 256B K/V gathers, per-head
// dot via shfl_xor(1,2,4), node-max over heads via shfl_xor(8,16,32).
// agg = (sum exp(score-m)*v) / (sum exp(score-m) + 1e-8).
// ---------------------------------------------------------------------------
__global__ __launch_bounds__(256) void agg_kernel(
    const float* __restrict__ Q, const float* __restrict__ K,
    const float* __restrict__ V,
    const int* __restrict__ cur, const int* __restrict__ deg,
    const int* __restrict__ elist, float* __restrict__ agg)
{
    int lane = threadIdx.x & 63;
    int n = blockIdx.x * 4 + (threadIdx.x >> 6);
    if (n >= N_NODES) return;

    int d = deg[n];
    int start = cur[n] - d;                   // cur[n] == segment end after scatter
    float qv = Q[n * 64 + lane];

    const float inv_scale = 0.35355339059327373f;  // 1/sqrt(8)
    float m = -INFINITY;
    float s = 0.f, acc = 0.f;

    for (int base = 0; base < d; base += 64) {
        int cnt = d - base; if (cnt > 64) cnt = 64;
        int ce = (lane < cnt) ? elist[start + base + lane] : 0;
        for (int j = 0; j < cnt; ++j) {
            int c = __shfl(ce, j);
            float kv = K[c * 64 + lane];
            float vv = V[c * 64 + lane];
            float p = qv * kv;
            p += __shfl_xor(p, 1);
            p += __shfl_xor(p, 2);
            p += __shfl_xor(p, 4);            // per-head dot (8 lanes share)
            float score = p * inv_scale;
            float em = score;
            em = fmaxf(em, __shfl_xor(em, 8));
            em = fmaxf(em, __shfl_xor(em, 16));
            em = fmaxf(em, __shfl_xor(em, 32)); // max over all heads (node-max candidate)
            float mn = fmaxf(m, em);
            float alpha = __expf(m - mn);       // exp(-inf)=0 on first edge
            float pe = __expf(score - mn);
            s = s * alpha + pe;
            acc = acc * alpha + pe * vv;
            m = mn;
        }
    }
    agg[n * 64 + lane] = acc / (s + 1e-8f);
}

// ---------------------------------------------------------------------------
// K7: output projection, in-place safe (row read fully into registers first).
// ---------------------------------------------------------------------------
__global__ __launch_bounds__(256) void out_kernel(
    const float* __restrict__ agg, const float* __restrict__ Wo,
    const float* __restrict__ bo, float* __restrict__ out)
{
    __shared__ float wo[64 * 64];
    __shared__ float sbo[64];
    int tid = threadIdx.x;
    for (int i = tid; i < 64 * 64; i += 256) wo[i] = Wo[i];
    if (tid < 64) sbo[tid] = bo[tid];
    __syncthreads();

    int lane = tid & 63;
    int wid = blockIdx.x * 4 + (tid >> 6);
    int nw = gridDim.x * 4;
    for (int n = wid; n < N_NODES; n += nw) {
        float av = agg[n * 64 + lane];
        float o = sbo[lane];
        #pragma unroll
        for (int k = 0; k < 64; ++k) {
            float ak = __shfl(av, k);
            o = fmaf(ak, wo[k * 64 + lane], o);
        }
        out[n * 64 + lane] = o;
    }
}

extern "C" void kernel_launch(void* const* d_in, const int* in_sizes, int n_in,
                              void* d_out, int out_size, void* d_ws, size_t ws_size,
                              hipStream_t stream)
{
    const float* x  = (const float*)d_in[0];
    const int*   ei = (const int*)  d_in[1];   // [2*E] flattened: row then col
    const float* Wq = (const float*)d_in[2];
    const float* bq = (const float*)d_in[3];
    const float* Wk = (const float*)d_in[4];
    const float* bk = (const float*)d_in[5];
    const float* Wv = (const float*)d_in[6];
    const float* bv = (const float*)d_in[7];
    const float* Wo = (const float*)d_in[8];
    const float* bo = (const float*)d_in[9];
    float* out = (float*)d_out;

    // workspace layout: Q,K,V (25.6MB each) + deg,cur (0.4MB each) + elist (6.4MB)
    float* Q = (float*)d_ws;
    float* K = Q + (size_t)N_NODES * 64;
    float* V = K + (size_t)N_NODES * 64;
    int* deg   = (int*)(V + (size_t)N_NODES * 64);
    int* cur   = deg + N_NODES;
    int* elist = cur + N_NODES;
    float* agg = out;   // park pre-projection agg in d_out; out_kernel is in-place safe

    hipMemsetAsync(deg, 0, N_NODES * sizeof(int), stream);

    qkv_kernel<<<2048, 256, 0, stream>>>(x, Wq, bq, Wk, bk, Wv, bv, Q, K, V);
    deg_kernel<<<(N_EDGES + 255) / 256, 256, 0, stream>>>(ei, deg);
    scan_kernel<<<1, 1024, 0, stream>>>(deg, cur);
    scatter_kernel<<<(N_EDGES + 255) / 256, 256, 0, stream>>>(ei, cur, elist);
    agg_kernel<<<(N_NODES + 3) / 4, 256, 0, stream>>>(Q, K, V, cur, deg, elist, agg);
    out_kernel<<<2048, 256, 0, stream>>>(agg, Wo, bo, out);
}

// Round 2
// 634.718 us; speedup vs baseline: 1.1474x; 1.1474x over previous
//
#include <hip/hip_runtime.h>
#include <hip/hip_bf16.h>
#include <math.h>

#define N_NODES 100000
#define N_EDGES 1600000

// ---------------------------------------------------------------------------
// K1: fused Q/K/V projection. Weights staged in LDS (48.75 KB). One wave per
// 8 nodes: lane l holds x[n_i, l] for i=0..7; one LDS read of W[k][l] feeds
// 8 FMAs (broadcast x_k via __shfl readlane). ds_reads/node: 192 -> 24.
// 100000 nodes = 3125 blocks * 4 waves * 8 nodes exactly (no tail).
// ---------------------------------------------------------------------------
__global__ __launch_bounds__(256) void qkv_kernel(
    const float* __restrict__ x,
    const float* __restrict__ Wq, const float* __restrict__ bq,
    const float* __restrict__ Wk, const float* __restrict__ bk,
    const float* __restrict__ Wv, const float* __restrict__ bv,
    float* __restrict__ Q, float* __restrict__ K, float* __restrict__ V)
{
    __shared__ float wq[64 * 64], wk[64 * 64], wv[64 * 64];
    __shared__ float sb[192];
    int tid = threadIdx.x;
    for (int i = tid; i < 64 * 64; i += 256) {
        wq[i] = Wq[i]; wk[i] = Wk[i]; wv[i] = Wv[i];
    }
    if (tid < 64) { sb[tid] = bq[tid]; sb[64 + tid] = bk[tid]; sb[128 + tid] = bv[tid]; }
    __syncthreads();

    int lane = tid & 63;
    int wid = blockIdx.x * 4 + (tid >> 6);
    int n0 = wid * 8;                      // wid < 12500 -> n0 < 100000 exact

    float xv[8];
    #pragma unroll
    for (int i = 0; i < 8; ++i) xv[i] = x[(n0 + i) * 64 + lane];

    float aq[8], ak[8], av[8];
    float bqv = sb[lane], bkv = sb[64 + lane], bvv = sb[128 + lane];
    #pragma unroll
    for (int i = 0; i < 8; ++i) { aq[i] = bqv; ak[i] = bkv; av[i] = bvv; }

    #pragma unroll
    for (int k = 0; k < 64; ++k) {
        float wqk = wq[k * 64 + lane];
        float wkk = wk[k * 64 + lane];
        float wvk = wv[k * 64 + lane];
        #pragma unroll
        for (int i = 0; i < 8; ++i) {
            float xk = __shfl(xv[i], k);
            aq[i] = fmaf(xk, wqk, aq[i]);
            ak[i] = fmaf(xk, wkk, ak[i]);
            av[i] = fmaf(xk, wvk, av[i]);
        }
    }
    #pragma unroll
    for (int i = 0; i < 8; ++i) {
        Q[(n0 + i) * 64 + lane] = aq[i];
        K[(n0 + i) * 64 + lane] = ak[i];
        V[(n0 + i) * 64 + lane] = av[i];
    }
}

// ---------------------------------------------------------------------------
// CSR build: histogram of source nodes -> exclusive scan -> scatter col ids.
// ---------------------------------------------------------------------------
__global__ void deg_kernel(const int* __restrict__ ei, int* __restrict__ deg)
{
    int t = blockIdx.x * blockDim.x + threadIdx.x;
    if (t < N_EDGES / 4) {
        int4 r = ((const int4*)ei)[t];
        atomicAdd(&deg[r.x], 1);
        atomicAdd(&deg[r.y], 1);
        atomicAdd(&deg[r.z], 1);
        atomicAdd(&deg[r.w], 1);
    }
}

__global__ __launch_bounds__(1024) void scan_kernel(
    const int* __restrict__ deg, int* __restrict__ cur)
{
    __shared__ int part[1024];
    int t = threadIdx.x;
    const int CH = (N_NODES + 1023) / 1024;   // 98 elems / thread
    int lo = t * CH;
    int hi = lo + CH; if (hi > N_NODES) hi = N_NODES;
    int s = 0;
    for (int i = lo; i < hi; ++i) s += deg[i];
    part[t] = s;
    __syncthreads();
    for (int off = 1; off < 1024; off <<= 1) {
        int v = (t >= off) ? part[t - off] : 0;
        __syncthreads();
        part[t] += v;
        __syncthreads();
    }
    int run = part[t] - s;                    // exclusive prefix for this chunk
    for (int i = lo; i < hi; ++i) { cur[i] = run; run += deg[i]; }
}

__global__ void scatter_kernel(const int* __restrict__ ei,
                               int* __restrict__ cur, int* __restrict__ elist)
{
    int t = blockIdx.x * blockDim.x + threadIdx.x;
    if (t < N_EDGES / 4) {
        int4 r = ((const int4*)ei)[t];
        int4 c = ((const int4*)(ei + N_EDGES))[t];
        int p0 = atomicAdd(&cur[r.x], 1); elist[p0] = c.x;
        int p1 = atomicAdd(&cur[r.y], 1); elist[p1] = c.y;
        int p2 = atomicAdd(&cur[r.z], 1); elist[p2] = c.z;
        int p3 = atomicAdd(&cur[r.w], 1); elist[p3] = c.w;
    }
}

// ---------------------------------------------------------------------------
// K6: per-node online-softmax aggregation, 8-edge batches (flash-style block
// update). One wave per node; lane l owns (head = l>>3, dim = l&7). Per batch:
// 8 independent coalesced 256B K/V gathers issued up-front (latency overlap),
// 8 per-head dots via shfl_xor(1,2,4), ONE cross-head/cross-edge max via
// shfl_xor(8,16,32), ONE rescale of (s, acc).
// ---------------------------------------------------------------------------
__global__ __launch_bounds__(256) void agg_kernel(
    const float* __restrict__ Q, const float* __restrict__ K,
    const float* __restrict__ V,
    const int* __restrict__ cur, const int* __restrict__ deg,
    const int* __restrict__ elist, float* __restrict__ agg)
{
    int lane = threadIdx.x & 63;
    int n = blockIdx.x * 4 + (threadIdx.x >> 6);
    if (n >= N_NODES) return;

    int d = deg[n];
    int start = cur[n] - d;                   // cur[n] == segment end after scatter
    float qv = Q[n * 64 + lane];

    const float inv_scale = 0.35355339059327373f;  // 1/sqrt(8)
    float m = -INFINITY;
    float s = 0.f, acc = 0.f;

    for (int base = 0; base < d; base += 64) {
        int cnt = d - base; if (cnt > 64) cnt = 64;
        int ce = elist[start + base + (lane < cnt ? lane : cnt - 1)];
        for (int j0 = 0; j0 < cnt; j0 += 8) {
            float kv[8], vv[8], sc[8];
            #pragma unroll
            for (int i = 0; i < 8; ++i) {          // issue all 8 gathers first
                int jj = j0 + i;
                int c = __shfl(ce, jj < cnt ? jj : 0);
                kv[i] = K[c * 64 + lane];
                vv[i] = V[c * 64 + lane];
            }
            #pragma unroll
            for (int i = 0; i < 8; ++i) {
                float p = qv * kv[i];
                p += __shfl_xor(p, 1);
                p += __shfl_xor(p, 2);
                p += __shfl_xor(p, 4);             // per-head dot
                sc[i] = (j0 + i < cnt) ? p * inv_scale : -INFINITY;
            }
            float em = sc[0];
            #pragma unroll
            for (int i = 1; i < 8; ++i) em = fmaxf(em, sc[i]);
            em = fmaxf(em, __shfl_xor(em, 8));
            em = fmaxf(em, __shfl_xor(em, 16));
            em = fmaxf(em, __shfl_xor(em, 32));    // max over heads & batch edges
            float mn = fmaxf(m, em);
            float alpha = __expf(m - mn);          // exp(-inf)=0 on first batch
            s *= alpha; acc *= alpha;
            #pragma unroll
            for (int i = 0; i < 8; ++i) {
                float pe = __expf(sc[i] - mn);     // padded lanes: exp(-inf)=0
                s += pe;
                acc = fmaf(pe, vv[i], acc);
            }
            m = mn;
        }
    }
    agg[n * 64 + lane] = acc / (s + 1e-8f);
}

// ---------------------------------------------------------------------------
// K7: output projection, 8 nodes per wave, in-place safe (rows read fully
// into registers before any write; row n depends only on agg row n).
// ---------------------------------------------------------------------------
__global__ __launch_bounds__(256) void out_kernel(
    const float* __restrict__ agg, const float* __restrict__ Wo,
    const float* __restrict__ bo, float* __restrict__ out)
{
    __shared__ float wo[64 * 64];
    __shared__ float sbo[64];
    int tid = threadIdx.x;
    for (int i = tid; i < 64 * 64; i += 256) wo[i] = Wo[i];
    if (tid < 64) sbo[tid] = bo[tid];
    __syncthreads();

    int lane = tid & 63;
    int wid = blockIdx.x * 4 + (tid >> 6);
    int n0 = wid * 8;

    float av[8], o[8];
    #pragma unroll
    for (int i = 0; i < 8; ++i) av[i] = agg[(n0 + i) * 64 + lane];
    float bov = sbo[lane];
    #pragma unroll
    for (int i = 0; i < 8; ++i) o[i] = bov;

    #pragma unroll
    for (int k = 0; k < 64; ++k) {
        float w = wo[k * 64 + lane];
        #pragma unroll
        for (int i = 0; i < 8; ++i) {
            float ak = __shfl(av[i], k);
            o[i] = fmaf(ak, w, o[i]);
        }
    }
    #pragma unroll
    for (int i = 0; i < 8; ++i) out[(n0 + i) * 64 + lane] = o[i];
}

extern "C" void kernel_launch(void* const* d_in, const int* in_sizes, int n_in,
                              void* d_out, int out_size, void* d_ws, size_t ws_size,
                              hipStream_t stream)
{
    const float* x  = (const float*)d_in[0];
    const int*   ei = (const int*)  d_in[1];   // [2*E] flattened: row then col
    const float* Wq = (const float*)d_in[2];
    const float* bq = (const float*)d_in[3];
    const float* Wk = (const float*)d_in[4];
    const float* bk = (const float*)d_in[5];
    const float* Wv = (const float*)d_in[6];
    const float* bv = (const float*)d_in[7];
    const float* Wo = (const float*)d_in[8];
    const float* bo = (const float*)d_in[9];
    float* out = (float*)d_out;

    float* Q = (float*)d_ws;
    float* K = Q + (size_t)N_NODES * 64;
    float* V = K + (size_t)N_NODES * 64;
    int* deg   = (int*)(V + (size_t)N_NODES * 64);
    int* cur   = deg + N_NODES;
    int* elist = cur + N_NODES;
    float* agg = out;   // park pre-projection agg in d_out; out_kernel is in-place safe

    hipMemsetAsync(deg, 0, N_NODES * sizeof(int), stream);

    qkv_kernel<<<3125, 256, 0, stream>>>(x, Wq, bq, Wk, bk, Wv, bv, Q, K, V);
    deg_kernel<<<(N_EDGES / 4 + 255) / 256, 256, 0, stream>>>(ei, deg);
    scan_kernel<<<1, 1024, 0, stream>>>(deg, cur);
    scatter_kernel<<<(N_EDGES / 4 + 255) / 256, 256, 0, stream>>>(ei, cur, elist);
    agg_kernel<<<(N_NODES + 3) / 4, 256, 0, stream>>>(Q, K, V, cur, deg, elist, agg);
    out_kernel<<<3125, 256, 0, stream>>>(agg, Wo, bo, out);
}

// Round 3
// 485.098 us; speedup vs baseline: 1.5013x; 1.3084x over previous
//
#include <hip/hip_runtime.h>
#include <hip/hip_bf16.h>
#include <math.h>

#define N_NODES 100000
#define N_EDGES 1600000
#define SCAN_CHUNK 512
#define SCAN_BLOCKS ((N_NODES + SCAN_CHUNK - 1) / SCAN_CHUNK)   // 196

// ---------------------------------------------------------------------------
// K1: fused Q/K/V projection. Weights staged in LDS (48.75 KB). One wave per
// 8 nodes: one LDS read of W[k][lane] feeds 8 FMAs (broadcast x_k via shfl).
// ---------------------------------------------------------------------------
__global__ __launch_bounds__(256) void qkv_kernel(
    const float* __restrict__ x,
    const float* __restrict__ Wq, const float* __restrict__ bq,
    const float* __restrict__ Wk, const float* __restrict__ bk,
    const float* __restrict__ Wv, const float* __restrict__ bv,
    float* __restrict__ Q, float* __restrict__ K, float* __restrict__ V)
{
    __shared__ float wq[64 * 64], wk[64 * 64], wv[64 * 64];
    __shared__ float sb[192];
    int tid = threadIdx.x;
    for (int i = tid; i < 64 * 64; i += 256) {
        wq[i] = Wq[i]; wk[i] = Wk[i]; wv[i] = Wv[i];
    }
    if (tid < 64) { sb[tid] = bq[tid]; sb[64 + tid] = bk[tid]; sb[128 + tid] = bv[tid]; }
    __syncthreads();

    int lane = tid & 63;
    int wid = blockIdx.x * 4 + (tid >> 6);
    int n0 = wid * 8;                      // wid < 12500 -> n0 < 100000 exact

    float xv[8];
    #pragma unroll
    for (int i = 0; i < 8; ++i) xv[i] = x[(n0 + i) * 64 + lane];

    float aq[8], ak[8], av[8];
    float bqv = sb[lane], bkv = sb[64 + lane], bvv = sb[128 + lane];
    #pragma unroll
    for (int i = 0; i < 8; ++i) { aq[i] = bqv; ak[i] = bkv; av[i] = bvv; }

    #pragma unroll
    for (int k = 0; k < 64; ++k) {
        float wqk = wq[k * 64 + lane];
        float wkk = wk[k * 64 + lane];
        float wvk = wv[k * 64 + lane];
        #pragma unroll
        for (int i = 0; i < 8; ++i) {
            float xk = __shfl(xv[i], k);
            aq[i] = fmaf(xk, wqk, aq[i]);
            ak[i] = fmaf(xk, wkk, ak[i]);
            av[i] = fmaf(xk, wvk, av[i]);
        }
    }
    #pragma unroll
    for (int i = 0; i < 8; ++i) {
        Q[(n0 + i) * 64 + lane] = aq[i];
        K[(n0 + i) * 64 + lane] = ak[i];
        V[(n0 + i) * 64 + lane] = av[i];
    }
}

// ---------------------------------------------------------------------------
// CSR build: histogram -> 3-kernel device scan -> scatter col ids.
// ---------------------------------------------------------------------------
__global__ void deg_kernel(const int* __restrict__ ei, int* __restrict__ deg)
{
    int t = blockIdx.x * blockDim.x + threadIdx.x;
    if (t < N_EDGES / 4) {
        int4 r = ((const int4*)ei)[t];
        atomicAdd(&deg[r.x], 1);
        atomicAdd(&deg[r.y], 1);
        atomicAdd(&deg[r.z], 1);
        atomicAdd(&deg[r.w], 1);
    }
}

// block sums: 196 blocks x 512 elems, coalesced
__global__ __launch_bounds__(256) void bsum_kernel(
    const int* __restrict__ deg, int* __restrict__ bsum)
{
    __shared__ int ws[4];
    int b = blockIdx.x, t = threadIdx.x;
    int base = b * SCAN_CHUNK;
    int s = 0;
    int i0 = base + t;       if (i0 < N_NODES) s += deg[i0];
    int i1 = base + 256 + t; if (i1 < N_NODES) s += deg[i1];
    #pragma unroll
    for (int off = 1; off < 64; off <<= 1) s += __shfl_xor(s, off);
    if ((t & 63) == 0) ws[t >> 6] = s;
    __syncthreads();
    if (t == 0) bsum[b] = ws[0] + ws[1] + ws[2] + ws[3];
}

// exclusive scan of the 196 block sums, in place (one block)
__global__ __launch_bounds__(256) void bscan_kernel(int* __restrict__ bsum)
{
    __shared__ int lds[256];
    int t = threadIdx.x;
    int v = (t < SCAN_BLOCKS) ? bsum[t] : 0;
    lds[t] = v;
    __syncthreads();
    for (int off = 1; off < 256; off <<= 1) {
        int u = (t >= off) ? lds[t - off] : 0;
        __syncthreads();
        lds[t] += u;
        __syncthreads();
    }
    if (t < SCAN_BLOCKS) bsum[t] = lds[t] - v;   // exclusive
}

// per-block exclusive scan + block offset -> cur (segment starts)
__global__ __launch_bounds__(256) void wscan_kernel(
    const int* __restrict__ deg, const int* __restrict__ bsum,
    int* __restrict__ cur)
{
    __shared__ int wsum[4];
    int b = blockIdx.x, t = threadIdx.x;
    int base = b * SCAN_CHUNK;
    int i0 = base + 2 * t;                 // N_NODES even -> pair all-in or all-out
    bool in = (i0 < N_NODES);
    int2 dd = in ? ((const int2*)deg)[(base >> 1) + t] : make_int2(0, 0);
    int local = dd.x + dd.y;

    int lane = t & 63, w = t >> 6;
    int inc = local;
    #pragma unroll
    for (int off = 1; off < 64; off <<= 1) {
        int u = __shfl_up(inc, off);
        if (lane >= off) inc += u;
    }
    if (lane == 63) wsum[w] = inc;
    __syncthreads();
    int woff = 0;
    for (int i = 0; i < w; ++i) woff += wsum[i];
    int excl = bsum[b] + woff + inc - local;
    if (in) {
        cur[i0]     = excl;
        cur[i0 + 1] = excl + dd.x;
    }
}

__global__ void scatter_kernel(const int* __restrict__ ei,
                               int* __restrict__ cur, int* __restrict__ elist)
{
    int t = blockIdx.x * blockDim.x + threadIdx.x;
    if (t < N_EDGES / 4) {
        int4 r = ((const int4*)ei)[t];
        int4 c = ((const int4*)(ei + N_EDGES))[t];
        int p0 = atomicAdd(&cur[r.x], 1); elist[p0] = c.x;
        int p1 = atomicAdd(&cur[r.y], 1); elist[p1] = c.y;
        int p2 = atomicAdd(&cur[r.z], 1); elist[p2] = c.z;
        int p3 = atomicAdd(&cur[r.w], 1); elist[p3] = c.w;
    }
}

// ---------------------------------------------------------------------------
// K6: per-node online-softmax aggregation, 8-edge batches (flash-style block
// update). One wave per node; lane l owns (head = l>>3, dim = l&7).
// ---------------------------------------------------------------------------
__global__ __launch_bounds__(256) void agg_kernel(
    const float* __restrict__ Q, const float* __restrict__ K,
    const float* __restrict__ V,
    const int* __restrict__ cur, const int* __restrict__ deg,
    const int* __restrict__ elist, float* __restrict__ agg)
{
    int lane = threadIdx.x & 63;
    int n = blockIdx.x * 4 + (threadIdx.x >> 6);
    if (n >= N_NODES) return;

    int d = deg[n];
    int start = cur[n] - d;                   // cur[n] == segment end after scatter
    float qv = Q[n * 64 + lane];

    const float inv_scale = 0.35355339059327373f;  // 1/sqrt(8)
    float m = -INFINITY;
    float s = 0.f, acc = 0.f;

    for (int base = 0; base < d; base += 64) {
        int cnt = d - base; if (cnt > 64) cnt = 64;
        int ce = elist[start + base + (lane < cnt ? lane : cnt - 1)];
        for (int j0 = 0; j0 < cnt; j0 += 8) {
            float kv[8], vv[8], sc[8];
            #pragma unroll
            for (int i = 0; i < 8; ++i) {          // issue all 8 gathers first
                int jj = j0 + i;
                int c = __shfl(ce, jj < cnt ? jj : 0);
                kv[i] = K[c * 64 + lane];
                vv[i] = V[c * 64 + lane];
            }
            #pragma unroll
            for (int i = 0; i < 8; ++i) {
                float p = qv * kv[i];
                p += __shfl_xor(p, 1);
                p += __shfl_xor(p, 2);
                p += __shfl_xor(p, 4);             // per-head dot
                sc[i] = (j0 + i < cnt) ? p * inv_scale : -INFINITY;
            }
            float em = sc[0];
            #pragma unroll
            for (int i = 1; i < 8; ++i) em = fmaxf(em, sc[i]);
            em = fmaxf(em, __shfl_xor(em, 8));
            em = fmaxf(em, __shfl_xor(em, 16));
            em = fmaxf(em, __shfl_xor(em, 32));    // max over heads & batch edges
            float mn = fmaxf(m, em);
            float alpha = __expf(m - mn);          // exp(-inf)=0 on first batch
            s *= alpha; acc *= alpha;
            #pragma unroll
            for (int i = 0; i < 8; ++i) {
                float pe = __expf(sc[i] - mn);     // padded lanes: exp(-inf)=0
                s += pe;
                acc = fmaf(pe, vv[i], acc);
            }
            m = mn;
        }
    }
    agg[n * 64 + lane] = acc / (s + 1e-8f);
}

// ---------------------------------------------------------------------------
// K7: output projection, 8 nodes per wave, in-place safe.
// ---------------------------------------------------------------------------
__global__ __launch_bounds__(256) void out_kernel(
    const float* __restrict__ agg, const float* __restrict__ Wo,
    const float* __restrict__ bo, float* __restrict__ out)
{
    __shared__ float wo[64 * 64];
    __shared__ float sbo[64];
    int tid = threadIdx.x;
    for (int i = tid; i < 64 * 64; i += 256) wo[i] = Wo[i];
    if (tid < 64) sbo[tid] = bo[tid];
    __syncthreads();

    int lane = tid & 63;
    int wid = blockIdx.x * 4 + (tid >> 6);
    int n0 = wid * 8;

    float av[8], o[8];
    #pragma unroll
    for (int i = 0; i < 8; ++i) av[i] = agg[(n0 + i) * 64 + lane];
    float bov = sbo[lane];
    #pragma unroll
    for (int i = 0; i < 8; ++i) o[i] = bov;

    #pragma unroll
    for (int k = 0; k < 64; ++k) {
        float w = wo[k * 64 + lane];
        #pragma unroll
        for (int i = 0; i < 8; ++i) {
            float ak = __shfl(av[i], k);
            o[i] = fmaf(ak, w, o[i]);
        }
    }
    #pragma unroll
    for (int i = 0; i < 8; ++i) out[(n0 + i) * 64 + lane] = o[i];
}

extern "C" void kernel_launch(void* const* d_in, const int* in_sizes, int n_in,
                              void* d_out, int out_size, void* d_ws, size_t ws_size,
                              hipStream_t stream)
{
    const float* x  = (const float*)d_in[0];
    const int*   ei = (const int*)  d_in[1];   // [2*E] flattened: row then col
    const float* Wq = (const float*)d_in[2];
    const float* bq = (const float*)d_in[3];
    const float* Wk = (const float*)d_in[4];
    const float* bk = (const float*)d_in[5];
    const float* Wv = (const float*)d_in[6];
    const float* bv = (const float*)d_in[7];
    const float* Wo = (const float*)d_in[8];
    const float* bo = (const float*)d_in[9];
    float* out = (float*)d_out;

    float* Q = (float*)d_ws;
    float* K = Q + (size_t)N_NODES * 64;
    float* V = K + (size_t)N_NODES * 64;
    int* deg   = (int*)(V + (size_t)N_NODES * 64);
    int* cur   = deg + N_NODES;
    int* elist = cur + N_NODES;
    int* bsum  = elist + N_EDGES;              // 196 ints
    float* agg = out;   // park pre-projection agg in d_out; out_kernel is in-place safe

    hipMemsetAsync(deg, 0, N_NODES * sizeof(int), stream);

    qkv_kernel<<<3125, 256, 0, stream>>>(x, Wq, bq, Wk, bk, Wv, bv, Q, K, V);
    deg_kernel<<<(N_EDGES / 4 + 255) / 256, 256, 0, stream>>>(ei, deg);
    bsum_kernel<<<SCAN_BLOCKS, 256, 0, stream>>>(deg, bsum);
    bscan_kernel<<<1, 256, 0, stream>>>(bsum);
    wscan_kernel<<<SCAN_BLOCKS, 256, 0, stream>>>(deg, bsum, cur);
    scatter_kernel<<<(N_EDGES / 4 + 255) / 256, 256, 0, stream>>>(ei, cur, elist);
    agg_kernel<<<(N_NODES + 3) / 4, 256, 0, stream>>>(Q, K, V, cur, deg, elist, agg);
    out_kernel<<<3125, 256, 0, stream>>>(agg, Wo, bo, out);
}

// Round 4
// 334.210 us; speedup vs baseline: 2.1791x; 1.4515x over previous
//
#include <hip/hip_runtime.h>
#include <hip/hip_bf16.h>
#include <math.h>

#define N_NODES 100000
#define N_EDGES 1600000
#define BUCKET_SHIFT 8
#define NBUCKETS ((N_NODES + 255) >> 8)      // 391 buckets of 256 nodes
#define BCAP 6144                            // mean 4096, sigma ~64 -> 32 sigma margin

// ---------------------------------------------------------------------------
// K1: fused Q/K/V projection. Weights staged in LDS (48.75 KB). One wave per
// 8 nodes: one LDS read of W[k][lane] feeds 8 FMAs (broadcast x_k via shfl).
// ---------------------------------------------------------------------------
__global__ __launch_bounds__(256) void qkv_kernel(
    const float* __restrict__ x,
    const float* __restrict__ Wq, const float* __restrict__ bq,
    const float* __restrict__ Wk, const float* __restrict__ bk,
    const float* __restrict__ Wv, const float* __restrict__ bv,
    float* __restrict__ Q, float* __restrict__ K, float* __restrict__ V)
{
    __shared__ float wq[64 * 64], wk[64 * 64], wv[64 * 64];
    __shared__ float sb[192];
    int tid = threadIdx.x;
    for (int i = tid; i < 64 * 64; i += 256) {
        wq[i] = Wq[i]; wk[i] = Wk[i]; wv[i] = Wv[i];
    }
    if (tid < 64) { sb[tid] = bq[tid]; sb[64 + tid] = bk[tid]; sb[128 + tid] = bv[tid]; }
    __syncthreads();

    int lane = tid & 63;
    int wid = blockIdx.x * 4 + (tid >> 6);
    int n0 = wid * 8;                      // wid < 12500 -> n0 < 100000 exact

    float xv[8];
    #pragma unroll
    for (int i = 0; i < 8; ++i) xv[i] = x[(n0 + i) * 64 + lane];

    float aq[8], ak[8], av[8];
    float bqv = sb[lane], bkv = sb[64 + lane], bvv = sb[128 + lane];
    #pragma unroll
    for (int i = 0; i < 8; ++i) { aq[i] = bqv; ak[i] = bkv; av[i] = bvv; }

    #pragma unroll
    for (int k = 0; k < 64; ++k) {
        float wqk = wq[k * 64 + lane];
        float wkk = wk[k * 64 + lane];
        float wvk = wv[k * 64 + lane];
        #pragma unroll
        for (int i = 0; i < 8; ++i) {
            float xk = __shfl(xv[i], k);
            aq[i] = fmaf(xk, wqk, aq[i]);
            ak[i] = fmaf(xk, wkk, ak[i]);
            av[i] = fmaf(xk, wvk, av[i]);
        }
    }
    #pragma unroll
    for (int i = 0; i < 8; ++i) {
        Q[(n0 + i) * 64 + lane] = aq[i];
        K[(n0 + i) * 64 + lane] = ak[i];
        V[(n0 + i) * 64 + lane] = av[i];
    }
}

// ---------------------------------------------------------------------------
// CSR build, bucketed. cursor[b] starts at b*BCAP (re-inited every launch).
// ---------------------------------------------------------------------------
__global__ void init_cursor_kernel(int* __restrict__ cursor)
{
    int t = threadIdx.x;
    if (t < NBUCKETS) cursor[t] = t * BCAP;
}

// Pass 1: bucket edges by row>>8. LDS histogram -> per-edge local rank
// (LDS atomic returns old), one global atomic per (block,bucket) reserves a
// range, then grouped stores of packed ((row&255)<<17 | col) into the bucket
// region. 8 edges/thread, all register indices compile-time.
__global__ __launch_bounds__(256) void bucket_scatter_kernel(
    const int* __restrict__ ei, int* __restrict__ cursor,
    unsigned int* __restrict__ pairs)
{
    __shared__ int hist[NBUCKETS];
    __shared__ int bbs[NBUCKETS];
    int t = threadIdx.x;
    for (int i = t; i < NBUCKETS; i += 256) hist[i] = 0;
    __syncthreads();

    const int4* r4 = (const int4*)ei;
    const int4* c4 = (const int4*)(ei + N_EDGES);
    int ia = blockIdx.x * 512 + t;
    int ib = ia + 256;
    bool va = (ia < N_EDGES / 4), vb = (ib < N_EDGES / 4);
    int4 rva = va ? r4[ia] : make_int4(0, 0, 0, 0);
    int4 cva = va ? c4[ia] : make_int4(0, 0, 0, 0);
    int4 rvb = vb ? r4[ib] : make_int4(0, 0, 0, 0);
    int4 cvb = vb ? c4[ib] : make_int4(0, 0, 0, 0);

    int rr[8], cc[8];
    rr[0] = rva.x; rr[1] = rva.y; rr[2] = rva.z; rr[3] = rva.w;
    rr[4] = rvb.x; rr[5] = rvb.y; rr[6] = rvb.z; rr[7] = rvb.w;
    cc[0] = cva.x; cc[1] = cva.y; cc[2] = cva.z; cc[3] = cva.w;
    cc[4] = cvb.x; cc[5] = cvb.y; cc[6] = cvb.z; cc[7] = cvb.w;

    int bkt[8], rnk[8];
    unsigned pk[8];
    #pragma unroll
    for (int j = 0; j < 8; ++j) {
        bool v = (j < 4) ? va : vb;
        int b = rr[j] >> BUCKET_SHIFT;
        bkt[j] = b;
        rnk[j] = v ? atomicAdd(&hist[b], 1) : 0;
        pk[j] = ((unsigned)(rr[j] & 255) << 17) | (unsigned)cc[j];
    }
    __syncthreads();
    for (int i = t; i < NBUCKETS; i += 256) {
        int h = hist[i];
        if (h) bbs[i] = atomicAdd(&cursor[i], h);
    }
    __syncthreads();
    #pragma unroll
    for (int j = 0; j < 8; ++j) {
        bool v = (j < 4) ? va : vb;
        if (v) pairs[bbs[bkt[j]] + rnk[j]] = pk[j];
    }
}

// Pass 2: exclusive scan of the 391 real bucket counts -> bucket edge bases.
__global__ __launch_bounds__(512) void bucket_scan_kernel(
    const int* __restrict__ cursor, int* __restrict__ bbase)
{
    __shared__ int lds[512];
    int t = threadIdx.x;
    int v = (t < NBUCKETS) ? (cursor[t] - t * BCAP) : 0;
    lds[t] = v;
    __syncthreads();
    for (int off = 1; off < 512; off <<= 1) {
        int u = (t >= off) ? lds[t - off] : 0;
        __syncthreads();
        lds[t] += u;
        __syncthreads();
    }
    if (t < NBUCKETS) bbase[t] = lds[t] - v;   // exclusive
}

// Pass 3: one block per bucket. LDS 256-bin histogram + scan -> deg/start and
// exact elist positions; stores confined to a ~16KB contiguous region.
__global__ __launch_bounds__(256) void csr_build_kernel(
    const unsigned int* __restrict__ pairs, const int* __restrict__ cursor,
    const int* __restrict__ bbase,
    int* __restrict__ deg, int* __restrict__ start, int* __restrict__ elist)
{
    __shared__ int hist[256], scn[256], lcur[256];
    int b = blockIdx.x, t = threadIdx.x;
    int cnt = cursor[b] - b * BCAP;
    int base = bbase[b];
    const unsigned int* bp = pairs + (size_t)b * BCAP;

    hist[t] = 0;
    __syncthreads();
    for (int i = t; i < cnt; i += 256)
        atomicAdd(&hist[bp[i] >> 17], 1);
    __syncthreads();

    int h = hist[t];
    scn[t] = h;
    __syncthreads();
    for (int off = 1; off < 256; off <<= 1) {
        int u = (t >= off) ? scn[t - off] : 0;
        __syncthreads();
        scn[t] += u;
        __syncthreads();
    }
    int excl = scn[t] - h;
    int node = (b << BUCKET_SHIFT) + t;
    if (node < N_NODES) { deg[node] = h; start[node] = base + excl; }
    lcur[t] = excl;
    __syncthreads();
    for (int i = t; i < cnt; i += 256) {
        unsigned p = bp[i];
        int pos = base + atomicAdd(&lcur[p >> 17], 1);
        elist[pos] = (int)(p & 0x1FFFFu);
    }
}

// ---------------------------------------------------------------------------
// K6: per-node online-softmax aggregation, 8-edge batches (flash-style block
// update). One wave per node; lane l owns (head = l>>3, dim = l&7).
// ---------------------------------------------------------------------------
__global__ __launch_bounds__(256) void agg_kernel(
    const float* __restrict__ Q, const float* __restrict__ K,
    const float* __restrict__ V,
    const int* __restrict__ start, const int* __restrict__ deg,
    const int* __restrict__ elist, float* __restrict__ agg)
{
    int lane = threadIdx.x & 63;
    int n = blockIdx.x * 4 + (threadIdx.x >> 6);
    if (n >= N_NODES) return;

    int d = deg[n];
    int st = start[n];
    float qv = Q[n * 64 + lane];

    const float inv_scale = 0.35355339059327373f;  // 1/sqrt(8)
    float m = -INFINITY;
    float s = 0.f, acc = 0.f;

    for (int base = 0; base < d; base += 64) {
        int cnt = d - base; if (cnt > 64) cnt = 64;
        int ce = elist[st + base + (lane < cnt ? lane : cnt - 1)];
        for (int j0 = 0; j0 < cnt; j0 += 8) {
            float kv[8], vv[8], sc[8];
            #pragma unroll
            for (int i = 0; i < 8; ++i) {          // issue all 8 gathers first
                int jj = j0 + i;
                int c = __shfl(ce, jj < cnt ? jj : 0);
                kv[i] = K[c * 64 + lane];
                vv[i] = V[c * 64 + lane];
            }
            #pragma unroll
            for (int i = 0; i < 8; ++i) {
                float p = qv * kv[i];
                p += __shfl_xor(p, 1);
                p += __shfl_xor(p, 2);
                p += __shfl_xor(p, 4);             // per-head dot
                sc[i] = (j0 + i < cnt) ? p * inv_scale : -INFINITY;
            }
            float em = sc[0];
            #pragma unroll
            for (int i = 1; i < 8; ++i) em = fmaxf(em, sc[i]);
            em = fmaxf(em, __shfl_xor(em, 8));
            em = fmaxf(em, __shfl_xor(em, 16));
            em = fmaxf(em, __shfl_xor(em, 32));    // max over heads & batch edges
            float mn = fmaxf(m, em);
            float alpha = __expf(m - mn);          // exp(-inf)=0 on first batch
            s *= alpha; acc *= alpha;
            #pragma unroll
            for (int i = 0; i < 8; ++i) {
                float pe = __expf(sc[i] - mn);     // padded lanes: exp(-inf)=0
                s += pe;
                acc = fmaf(pe, vv[i], acc);
            }
            m = mn;
        }
    }
    agg[n * 64 + lane] = acc / (s + 1e-8f);
}

// ---------------------------------------------------------------------------
// K7: output projection, 8 nodes per wave, in-place safe.
// ---------------------------------------------------------------------------
__global__ __launch_bounds__(256) void out_kernel(
    const float* __restrict__ agg, const float* __restrict__ Wo,
    const float* __restrict__ bo, float* __restrict__ out)
{
    __shared__ float wo[64 * 64];
    __shared__ float sbo[64];
    int tid = threadIdx.x;
    for (int i = tid; i < 64 * 64; i += 256) wo[i] = Wo[i];
    if (tid < 64) sbo[tid] = bo[tid];
    __syncthreads();

    int lane = tid & 63;
    int wid = blockIdx.x * 4 + (tid >> 6);
    int n0 = wid * 8;

    float av[8], o[8];
    #pragma unroll
    for (int i = 0; i < 8; ++i) av[i] = agg[(n0 + i) * 64 + lane];
    float bov = sbo[lane];
    #pragma unroll
    for (int i = 0; i < 8; ++i) o[i] = bov;

    #pragma unroll
    for (int k = 0; k < 64; ++k) {
        float w = wo[k * 64 + lane];
        #pragma unroll
        for (int i = 0; i < 8; ++i) {
            float ak = __shfl(av[i], k);
            o[i] = fmaf(ak, w, o[i]);
        }
    }
    #pragma unroll
    for (int i = 0; i < 8; ++i) out[(n0 + i) * 64 + lane] = o[i];
}

extern "C" void kernel_launch(void* const* d_in, const int* in_sizes, int n_in,
                              void* d_out, int out_size, void* d_ws, size_t ws_size,
                              hipStream_t stream)
{
    const float* x  = (const float*)d_in[0];
    const int*   ei = (const int*)  d_in[1];   // [2*E] flattened: row then col
    const float* Wq = (const float*)d_in[2];
    const float* bq = (const float*)d_in[3];
    const float* Wk = (const float*)d_in[4];
    const float* bk = (const float*)d_in[5];
    const float* Wv = (const float*)d_in[6];
    const float* bv = (const float*)d_in[7];
    const float* Wo = (const float*)d_in[8];
    const float* bo = (const float*)d_in[9];
    float* out = (float*)d_out;

    float* Q = (float*)d_ws;
    float* K = Q + (size_t)N_NODES * 64;
    float* V = K + (size_t)N_NODES * 64;
    int* deg    = (int*)(V + (size_t)N_NODES * 64);
    int* start  = deg + N_NODES;
    int* elist  = start + N_NODES;
    int* cursor = elist + N_EDGES;                   // NBUCKETS ints
    int* bbase  = cursor + 512;
    unsigned int* pairs = (unsigned int*)(bbase + 512);  // NBUCKETS*BCAP
    float* agg = out;   // park pre-projection agg in d_out; out_kernel is in-place safe

    init_cursor_kernel<<<1, 512, 0, stream>>>(cursor);
    qkv_kernel<<<3125, 256, 0, stream>>>(x, Wq, bq, Wk, bk, Wv, bv, Q, K, V);
    bucket_scatter_kernel<<<(N_EDGES / 4 + 511) / 512, 256, 0, stream>>>(ei, cursor, pairs);
    bucket_scan_kernel<<<1, 512, 0, stream>>>(cursor, bbase);
    csr_build_kernel<<<NBUCKETS, 256, 0, stream>>>(pairs, cursor, bbase, deg, start, elist);
    agg_kernel<<<(N_NODES + 3) / 4, 256, 0, stream>>>(Q, K, V, start, deg, elist, agg);
    out_kernel<<<3125, 256, 0, stream>>>(agg, Wo, bo, out);
}

// Round 5
// 326.004 us; speedup vs baseline: 2.2340x; 1.0252x over previous
//
#include <hip/hip_runtime.h>
#include <hip/hip_bf16.h>
#include <math.h>

#define N_NODES 100000
#define N_EDGES 1600000
#define BUCKET_SHIFT 8
#define NBUCKETS ((N_NODES + 255) >> 8)      // 391 buckets of 256 nodes
#define BCAP 6144                            // mean 4096, sigma ~64 -> 32 sigma margin

// ---------------------------------------------------------------------------
// K1: fused Q/KV projection. Weights staged in LDS (48.75 KB). One wave per
// 8 nodes: one LDS read of W[k][lane] feeds 8 FMAs (broadcast x_k via shfl).
// K and V interleaved into one KV[n][128] row so agg computes ONE gather
// address per edge. Block 0 also re-inits the bucket cursors (visible to the
// next kernel at the dispatch boundary).
// ---------------------------------------------------------------------------
__global__ __launch_bounds__(256) void qkv_kernel(
    const float* __restrict__ x,
    const float* __restrict__ Wq, const float* __restrict__ bq,
    const float* __restrict__ Wk, const float* __restrict__ bk,
    const float* __restrict__ Wv, const float* __restrict__ bv,
    float* __restrict__ Q, float* __restrict__ KV, int* __restrict__ cursor)
{
    __shared__ float wq[64 * 64], wk[64 * 64], wv[64 * 64];
    __shared__ float sb[192];
    int tid = threadIdx.x;
    if (blockIdx.x == 0) {
        for (int i = tid; i < NBUCKETS; i += 256) cursor[i] = i * BCAP;
    }
    for (int i = tid; i < 64 * 64; i += 256) {
        wq[i] = Wq[i]; wk[i] = Wk[i]; wv[i] = Wv[i];
    }
    if (tid < 64) { sb[tid] = bq[tid]; sb[64 + tid] = bk[tid]; sb[128 + tid] = bv[tid]; }
    __syncthreads();

    int lane = tid & 63;
    int wid = blockIdx.x * 4 + (tid >> 6);
    int n0 = wid * 8;                      // wid < 12500 -> n0 < 100000 exact

    float xv[8];
    #pragma unroll
    for (int i = 0; i < 8; ++i) xv[i] = x[(n0 + i) * 64 + lane];

    float aq[8], ak[8], av[8];
    float bqv = sb[lane], bkv = sb[64 + lane], bvv = sb[128 + lane];
    #pragma unroll
    for (int i = 0; i < 8; ++i) { aq[i] = bqv; ak[i] = bkv; av[i] = bvv; }

    #pragma unroll
    for (int k = 0; k < 64; ++k) {
        float wqk = wq[k * 64 + lane];
        float wkk = wk[k * 64 + lane];
        float wvk = wv[k * 64 + lane];
        #pragma unroll
        for (int i = 0; i < 8; ++i) {
            float xk = __shfl(xv[i], k);
            aq[i] = fmaf(xk, wqk, aq[i]);
            ak[i] = fmaf(xk, wkk, ak[i]);
            av[i] = fmaf(xk, wvk, av[i]);
        }
    }
    #pragma unroll
    for (int i = 0; i < 8; ++i) {
        Q[(n0 + i) * 64 + lane] = aq[i];
        KV[(n0 + i) * 128 + lane] = ak[i];
        KV[(n0 + i) * 128 + 64 + lane] = av[i];
    }
}

// ---------------------------------------------------------------------------
// Pass 1: bucket edges by row>>8. LDS histogram -> per-edge local rank, one
// global atomic per (block,bucket) reserves a range, grouped stores of packed
// ((row&255)<<17 | col) into the bucket region.
// ---------------------------------------------------------------------------
__global__ __launch_bounds__(256) void bucket_scatter_kernel(
    const int* __restrict__ ei, int* __restrict__ cursor,
    unsigned int* __restrict__ pairs)
{
    __shared__ int hist[NBUCKETS];
    __shared__ int bbs[NBUCKETS];
    int t = threadIdx.x;
    for (int i = t; i < NBUCKETS; i += 256) hist[i] = 0;
    __syncthreads();

    const int4* r4 = (const int4*)ei;
    const int4* c4 = (const int4*)(ei + N_EDGES);
    int ia = blockIdx.x * 512 + t;
    int ib = ia + 256;
    bool va = (ia < N_EDGES / 4), vb = (ib < N_EDGES / 4);
    int4 rva = va ? r4[ia] : make_int4(0, 0, 0, 0);
    int4 cva = va ? c4[ia] : make_int4(0, 0, 0, 0);
    int4 rvb = vb ? r4[ib] : make_int4(0, 0, 0, 0);
    int4 cvb = vb ? c4[ib] : make_int4(0, 0, 0, 0);

    int rr[8], cc[8];
    rr[0] = rva.x; rr[1] = rva.y; rr[2] = rva.z; rr[3] = rva.w;
    rr[4] = rvb.x; rr[5] = rvb.y; rr[6] = rvb.z; rr[7] = rvb.w;
    cc[0] = cva.x; cc[1] = cva.y; cc[2] = cva.z; cc[3] = cva.w;
    cc[4] = cvb.x; cc[5] = cvb.y; cc[6] = cvb.z; cc[7] = cvb.w;

    int bkt[8], rnk[8];
    unsigned pk[8];
    #pragma unroll
    for (int j = 0; j < 8; ++j) {
        bool v = (j < 4) ? va : vb;
        int b = rr[j] >> BUCKET_SHIFT;
        bkt[j] = b;
        rnk[j] = v ? atomicAdd(&hist[b], 1) : 0;
        pk[j] = ((unsigned)(rr[j] & 255) << 17) | (unsigned)cc[j];
    }
    __syncthreads();
    for (int i = t; i < NBUCKETS; i += 256) {
        int h = hist[i];
        if (h) bbs[i] = atomicAdd(&cursor[i], h);
    }
    __syncthreads();
    #pragma unroll
    for (int j = 0; j < 8; ++j) {
        bool v = (j < 4) ? va : vb;
        if (v) pairs[bbs[bkt[j]] + rnk[j]] = pk[j];
    }
}

// ---------------------------------------------------------------------------
// Pass 2: one block per bucket. Stage pairs in LDS, 256-bin histogram + scan
// -> deg/start; write ordered col ids back IN PLACE (elist aliases pairs,
// padded at b*BCAP). start[n] = b*BCAP + excl.
// ---------------------------------------------------------------------------
__global__ __launch_bounds__(256) void csr_build_kernel(
    unsigned int* __restrict__ pairs, const int* __restrict__ cursor,
    int* __restrict__ deg, int* __restrict__ start)
{
    __shared__ unsigned int lp[BCAP];        // 24 KB
    __shared__ int hist[256], scn[256];
    int b = blockIdx.x, t = threadIdx.x;
    int cnt = cursor[b] - b * BCAP;
    unsigned int* bp = pairs + (size_t)b * BCAP;

    for (int i = t; i < cnt; i += 256) lp[i] = bp[i];
    hist[t] = 0;
    __syncthreads();
    for (int i = t; i < cnt; i += 256) atomicAdd(&hist[lp[i] >> 17], 1);
    __syncthreads();

    int h = hist[t];
    scn[t] = h;
    __syncthreads();
    for (int off = 1; off < 256; off <<= 1) {
        int u = (t >= off) ? scn[t - off] : 0;
        __syncthreads();
        scn[t] += u;
        __syncthreads();
    }
    int excl = scn[t] - h;
    int node = (b << BUCKET_SHIFT) + t;
    if (node < N_NODES) { deg[node] = h; start[node] = b * BCAP + excl; }
    hist[t] = excl;                          // reuse as local cursor
    __syncthreads();
    for (int i = t; i < cnt; i += 256) {
        unsigned p = lp[i];
        int pos = atomicAdd(&hist[p >> 17], 1);
        bp[pos] = p & 0x1FFFFu;              // ordered col id, in place
    }
}

// ---------------------------------------------------------------------------
// K6: per-node online-softmax aggregation + FUSED Wo projection epilogue.
// One wave per node (100000 = 25000 blocks * 4 waves, exact). Lane l owns
// (head = l>>3, dim = l&7). Clean unmasked 8-edge batches + one masked tail.
// ---------------------------------------------------------------------------
#define AGG_BATCH(LIM_EXPR)                                                   \
    {                                                                         \
        float kvv[8], vvv[8], sc[8];                                          \
        _Pragma("unroll")                                                     \
        for (int i = 0; i < 8; ++i) {                                         \
            int jj = j0 + i;                                                  \
            int c = __shfl(ce, (jj < (LIM_EXPR)) ? jj : 0);                   \
            kvv[i] = KV[c * 128 + lane];                                      \
            vvv[i] = KV[c * 128 + 64 + lane];                                 \
        }                                                                     \
        _Pragma("unroll")                                                     \
        for (int i = 0; i < 8; ++i) {                                         \
            float p = qv * kvv[i];                                            \
            p += __shfl_xor(p, 1);                                            \
            p += __shfl_xor(p, 2);                                            \
            p += __shfl_xor(p, 4);                                            \
            sc[i] = (j0 + i < (LIM_EXPR)) ? p * inv_scale : -INFINITY;        \
        }                                                                     \
        float em = sc[0];                                                     \
        _Pragma("unroll")                                                     \
        for (int i = 1; i < 8; ++i) em = fmaxf(em, sc[i]);                    \
        em = fmaxf(em, __shfl_xor(em, 8));                                    \
        em = fmaxf(em, __shfl_xor(em, 16));                                   \
        em = fmaxf(em, __shfl_xor(em, 32));                                   \
        float mn = fmaxf(m, em);                                              \
        float alpha = __expf(m - mn);                                         \
        s *= alpha; acc *= alpha;                                             \
        _Pragma("unroll")                                                     \
        for (int i = 0; i < 8; ++i) {                                         \
            float pe = __expf(sc[i] - mn);                                    \
            s += pe;                                                          \
            acc = fmaf(pe, vvv[i], acc);                                      \
        }                                                                     \
        m = mn;                                                               \
    }

#define CLEAN_BATCH                                                           \
    {                                                                         \
        float kvv[8], vvv[8], sc[8];                                          \
        _Pragma("unroll")                                                     \
        for (int i = 0; i < 8; ++i) {                                         \
            int c = __shfl(ce, j0 + i);                                       \
            kvv[i] = KV[c * 128 + lane];                                      \
            vvv[i] = KV[c * 128 + 64 + lane];                                 \
        }                                                                     \
        _Pragma("unroll")                                                     \
        for (int i = 0; i < 8; ++i) {                                         \
            float p = qv * kvv[i];                                            \
            p += __shfl_xor(p, 1);                                            \
            p += __shfl_xor(p, 2);                                            \
            p += __shfl_xor(p, 4);                                            \
            sc[i] = p * inv_scale;                                            \
        }                                                                     \
        float em = sc[0];                                                     \
        _Pragma("unroll")                                                     \
        for (int i = 1; i < 8; ++i) em = fmaxf(em, sc[i]);                    \
        em = fmaxf(em, __shfl_xor(em, 8));                                    \
        em = fmaxf(em, __shfl_xor(em, 16));                                   \
        em = fmaxf(em, __shfl_xor(em, 32));                                   \
        float mn = fmaxf(m, em);                                              \
        float alpha = __expf(m - mn);                                         \
        s *= alpha; acc *= alpha;                                             \
        _Pragma("unroll")                                                     \
        for (int i = 0; i < 8; ++i) {                                         \
            float pe = __expf(sc[i] - mn);                                    \
            s += pe;                                                          \
            acc = fmaf(pe, vvv[i], acc);                                      \
        }                                                                     \
        m = mn;                                                               \
    }

__global__ __launch_bounds__(256) void agg_kernel(
    const float* __restrict__ Q, const float* __restrict__ KV,
    const int* __restrict__ start, const int* __restrict__ deg,
    const int* __restrict__ elist,
    const float* __restrict__ Wo, const float* __restrict__ bo,
    float* __restrict__ out)
{
    __shared__ float wo[64 * 64];
    __shared__ float sbo[64];
    int tid = threadIdx.x;
    for (int i = tid; i < 64 * 64; i += 256) wo[i] = Wo[i];
    if (tid < 64) sbo[tid] = bo[tid];
    __syncthreads();

    int lane = tid & 63;
    int n = blockIdx.x * 4 + (tid >> 6);     // grid 25000 -> n < 100000 exact

    int d = deg[n];
    int st = start[n];
    float qv = Q[n * 64 + lane];

    const float inv_scale = 0.35355339059327373f;  // 1/sqrt(8)
    float m = -INFINITY;
    float s = 0.f, acc = 0.f;

    for (int blk = 0; blk < d; blk += 64) {
        int cnt = d - blk; if (cnt > 64) cnt = 64;
        int ce = elist[st + blk + (lane < cnt ? lane : 0)];
        int j0 = 0;
        for (; j0 + 8 <= cnt; j0 += 8) CLEAN_BATCH
        if (j0 < cnt) AGG_BATCH(cnt)
    }
    float aggv = acc / (s + 1e-8f);

    // fused output projection: o = bo + sum_k agg[k] * Wo[k][lane]
    float o = sbo[lane];
    #pragma unroll
    for (int k = 0; k < 64; ++k) {
        float ak = __shfl(aggv, k);
        o = fmaf(ak, wo[k * 64 + lane], o);
    }
    out[n * 64 + lane] = o;
}

extern "C" void kernel_launch(void* const* d_in, const int* in_sizes, int n_in,
                              void* d_out, int out_size, void* d_ws, size_t ws_size,
                              hipStream_t stream)
{
    const float* x  = (const float*)d_in[0];
    const int*   ei = (const int*)  d_in[1];   // [2*E] flattened: row then col
    const float* Wq = (const float*)d_in[2];
    const float* bq = (const float*)d_in[3];
    const float* Wk = (const float*)d_in[4];
    const float* bk = (const float*)d_in[5];
    const float* Wv = (const float*)d_in[6];
    const float* bv = (const float*)d_in[7];
    const float* Wo = (const float*)d_in[8];
    const float* bo = (const float*)d_in[9];
    float* out = (float*)d_out;

    float* Q  = (float*)d_ws;                            // N*64
    float* KV = Q + (size_t)N_NODES * 64;                // N*128 interleaved
    int* deg    = (int*)(KV + (size_t)N_NODES * 128);
    int* start  = deg + N_NODES;
    int* cursor = start + N_NODES;                       // NBUCKETS ints
    unsigned int* pairs = (unsigned int*)(cursor + 512); // NBUCKETS*BCAP (elist aliases)

    qkv_kernel<<<3125, 256, 0, stream>>>(x, Wq, bq, Wk, bk, Wv, bv, Q, KV, cursor);
    bucket_scatter_kernel<<<(N_EDGES / 4 + 511) / 512, 256, 0, stream>>>(ei, cursor, pairs);
    csr_build_kernel<<<NBUCKETS, 256, 0, stream>>>(pairs, cursor, deg, start);
    agg_kernel<<<25000, 256, 0, stream>>>(Q, KV, start, deg, (const int*)pairs, Wo, bo, out);
}

// Round 6
// 321.628 us; speedup vs baseline: 2.2644x; 1.0136x over previous
//
#include <hip/hip_runtime.h>
#include <hip/hip_bf16.h>
#include <math.h>

#define N_NODES 100000
#define N_EDGES 1600000
#define BUCKET_SHIFT 8
#define NBUCKETS ((N_NODES + 255) >> 8)      // 391 buckets of 256 nodes
#define BCAP 6144                            // mean 4096, sigma ~64 -> 32 sigma margin

// ---------------------------------------------------------------------------
// K1: fused Q/KV projection. Weights staged in LDS (48.75 KB). One wave per
// 8 nodes: one LDS read of W[k][lane] feeds 8 FMAs (broadcast x_k via shfl).
// K and V interleaved into one KV[n][128] row so agg computes ONE gather
// address per edge. Block 0 also re-inits the bucket cursors.
// ---------------------------------------------------------------------------
__global__ __launch_bounds__(256) void qkv_kernel(
    const float* __restrict__ x,
    const float* __restrict__ Wq, const float* __restrict__ bq,
    const float* __restrict__ Wk, const float* __restrict__ bk,
    const float* __restrict__ Wv, const float* __restrict__ bv,
    float* __restrict__ Q, float* __restrict__ KV, int* __restrict__ cursor)
{
    __shared__ float wq[64 * 64], wk[64 * 64], wv[64 * 64];
    __shared__ float sb[192];
    int tid = threadIdx.x;
    if (blockIdx.x == 0) {
        for (int i = tid; i < NBUCKETS; i += 256) cursor[i] = i * BCAP;
    }
    for (int i = tid; i < 64 * 64; i += 256) {
        wq[i] = Wq[i]; wk[i] = Wk[i]; wv[i] = Wv[i];
    }
    if (tid < 64) { sb[tid] = bq[tid]; sb[64 + tid] = bk[tid]; sb[128 + tid] = bv[tid]; }
    __syncthreads();

    int lane = tid & 63;
    int wid = blockIdx.x * 4 + (tid >> 6);
    int n0 = wid * 8;                      // wid < 12500 -> n0 < 100000 exact

    float xv[8];
    #pragma unroll
    for (int i = 0; i < 8; ++i) xv[i] = x[(n0 + i) * 64 + lane];

    float aq[8], ak[8], av[8];
    float bqv = sb[lane], bkv = sb[64 + lane], bvv = sb[128 + lane];
    #pragma unroll
    for (int i = 0; i < 8; ++i) { aq[i] = bqv; ak[i] = bkv; av[i] = bvv; }

    #pragma unroll
    for (int k = 0; k < 64; ++k) {
        float wqk = wq[k * 64 + lane];
        float wkk = wk[k * 64 + lane];
        float wvk = wv[k * 64 + lane];
        #pragma unroll
        for (int i = 0; i < 8; ++i) {
            float xk = __shfl(xv[i], k);
            aq[i] = fmaf(xk, wqk, aq[i]);
            ak[i] = fmaf(xk, wkk, ak[i]);
            av[i] = fmaf(xk, wvk, av[i]);
        }
    }
    #pragma unroll
    for (int i = 0; i < 8; ++i) {
        Q[(n0 + i) * 64 + lane] = aq[i];
        KV[(n0 + i) * 128 + lane] = ak[i];
        KV[(n0 + i) * 128 + 64 + lane] = av[i];
    }
}

// ---------------------------------------------------------------------------
// Pass 1: bucket edges by row>>8. LDS histogram -> per-edge local rank, one
// global atomic per (block,bucket) reserves a range, grouped stores of packed
// ((row&255)<<17 | col) into the bucket region.
// ---------------------------------------------------------------------------
__global__ __launch_bounds__(256) void bucket_scatter_kernel(
    const int* __restrict__ ei, int* __restrict__ cursor,
    unsigned int* __restrict__ pairs)
{
    __shared__ int hist[NBUCKETS];
    __shared__ int bbs[NBUCKETS];
    int t = threadIdx.x;
    for (int i = t; i < NBUCKETS; i += 256) hist[i] = 0;
    __syncthreads();

    const int4* r4 = (const int4*)ei;
    const int4* c4 = (const int4*)(ei + N_EDGES);
    int ia = blockIdx.x * 512 + t;
    int ib = ia + 256;
    bool va = (ia < N_EDGES / 4), vb = (ib < N_EDGES / 4);
    int4 rva = va ? r4[ia] : make_int4(0, 0, 0, 0);
    int4 cva = va ? c4[ia] : make_int4(0, 0, 0, 0);
    int4 rvb = vb ? r4[ib] : make_int4(0, 0, 0, 0);
    int4 cvb = vb ? c4[ib] : make_int4(0, 0, 0, 0);

    int rr[8], cc[8];
    rr[0] = rva.x; rr[1] = rva.y; rr[2] = rva.z; rr[3] = rva.w;
    rr[4] = rvb.x; rr[5] = rvb.y; rr[6] = rvb.z; rr[7] = rvb.w;
    cc[0] = cva.x; cc[1] = cva.y; cc[2] = cva.z; cc[3] = cva.w;
    cc[4] = cvb.x; cc[5] = cvb.y; cc[6] = cvb.z; cc[7] = cvb.w;

    int bkt[8], rnk[8];
    unsigned pk[8];
    #pragma unroll
    for (int j = 0; j < 8; ++j) {
        bool v = (j < 4) ? va : vb;
        int b = rr[j] >> BUCKET_SHIFT;
        bkt[j] = b;
        rnk[j] = v ? atomicAdd(&hist[b], 1) : 0;
        pk[j] = ((unsigned)(rr[j] & 255) << 17) | (unsigned)cc[j];
    }
    __syncthreads();
    for (int i = t; i < NBUCKETS; i += 256) {
        int h = hist[i];
        if (h) bbs[i] = atomicAdd(&cursor[i], h);
    }
    __syncthreads();
    #pragma unroll
    for (int j = 0; j < 8; ++j) {
        bool v = (j < 4) ? va : vb;
        if (v) pairs[bbs[bkt[j]] + rnk[j]] = pk[j];
    }
}

// ---------------------------------------------------------------------------
// Pass 2: one block per bucket. Stage pairs in LDS, 256-bin histogram + scan
// -> deg/start; write ordered col ids back IN PLACE (elist aliases pairs,
// padded at b*BCAP). start[n] = b*BCAP + excl.
// ---------------------------------------------------------------------------
__global__ __launch_bounds__(256) void csr_build_kernel(
    unsigned int* __restrict__ pairs, const int* __restrict__ cursor,
    int* __restrict__ deg, int* __restrict__ start)
{
    __shared__ unsigned int lp[BCAP];        // 24 KB
    __shared__ int hist[256], scn[256];
    int b = blockIdx.x, t = threadIdx.x;
    int cnt = cursor[b] - b * BCAP;
    unsigned int* bp = pairs + (size_t)b * BCAP;

    for (int i = t; i < cnt; i += 256) lp[i] = bp[i];
    hist[t] = 0;
    __syncthreads();
    for (int i = t; i < cnt; i += 256) atomicAdd(&hist[lp[i] >> 17], 1);
    __syncthreads();

    int h = hist[t];
    scn[t] = h;
    __syncthreads();
    for (int off = 1; off < 256; off <<= 1) {
        int u = (t >= off) ? scn[t - off] : 0;
        __syncthreads();
        scn[t] += u;
        __syncthreads();
    }
    int excl = scn[t] - h;
    int node = (b << BUCKET_SHIFT) + t;
    if (node < N_NODES) { deg[node] = h; start[node] = b * BCAP + excl; }
    hist[t] = excl;                          // reuse as local cursor
    __syncthreads();
    for (int i = t; i < cnt; i += 256) {
        unsigned p = lp[i];
        int pos = atomicAdd(&hist[p >> 17], 1);
        bp[pos] = p & 0x1FFFFu;              // ordered col id, in place
    }
}

// ---------------------------------------------------------------------------
// K6: per-node online-softmax aggregation + fused Wo projection.
// T14 async-STAGE: Wo is loaded to REGISTERS at kernel entry (loads in
// flight during the whole gather loop), written to LDS + barrier only at
// the epilogue. One wave per node; lane l owns (head = l>>3, dim = l&7).
// ---------------------------------------------------------------------------
#define AGG_BATCH(LIM_EXPR)                                                   \
    {                                                                         \
        float kvv[8], vvv[8], sc[8];                                          \
        _Pragma("unroll")                                                     \
        for (int i = 0; i < 8; ++i) {                                         \
            int jj = j0 + i;                                                  \
            int c = __shfl(ce, (jj < (LIM_EXPR)) ? jj : 0);                   \
            kvv[i] = KV[c * 128 + lane];                                      \
            vvv[i] = KV[c * 128 + 64 + lane];                                 \
        }                                                                     \
        _Pragma("unroll")                                                     \
        for (int i = 0; i < 8; ++i) {                                         \
            float p = qv * kvv[i];                                            \
            p += __shfl_xor(p, 1);                                            \
            p += __shfl_xor(p, 2);                                            \
            p += __shfl_xor(p, 4);                                            \
            sc[i] = (j0 + i < (LIM_EXPR)) ? p * inv_scale : -INFINITY;        \
        }                                                                     \
        float em = sc[0];                                                     \
        _Pragma("unroll")                                                     \
        for (int i = 1; i < 8; ++i) em = fmaxf(em, sc[i]);                    \
        em = fmaxf(em, __shfl_xor(em, 8));                                    \
        em = fmaxf(em, __shfl_xor(em, 16));                                   \
        em = fmaxf(em, __shfl_xor(em, 32));                                   \
        float mn = fmaxf(m, em);                                              \
        float alpha = __expf(m - mn);                                         \
        s *= alpha; acc *= alpha;                                             \
        _Pragma("unroll")                                                     \
        for (int i = 0; i < 8; ++i) {                                         \
            float pe = __expf(sc[i] - mn);                                    \
            s += pe;                                                          \
            acc = fmaf(pe, vvv[i], acc);                                      \
        }                                                                     \
        m = mn;                                                               \
    }

#define CLEAN_BATCH                                                           \
    {                                                                         \
        float kvv[8], vvv[8], sc[8];                                          \
        _Pragma("unroll")                                                     \
        for (int i = 0; i < 8; ++i) {                                         \
            int c = __shfl(ce, j0 + i);                                       \
            kvv[i] = KV[c * 128 + lane];                                      \
            vvv[i] = KV[c * 128 + 64 + lane];                                 \
        }                                                                     \
        _Pragma("unroll")                                                     \
        for (int i = 0; i < 8; ++i) {                                         \
            float p = qv * kvv[i];                                            \
            p += __shfl_xor(p, 1);                                            \
            p += __shfl_xor(p, 2);                                            \
            p += __shfl_xor(p, 4);                                            \
            sc[i] = p * inv_scale;                                            \
        }                                                                     \
        float em = sc[0];                                                     \
        _Pragma("unroll")                                                     \
        for (int i = 1; i < 8; ++i) em = fmaxf(em, sc[i]);                    \
        em = fmaxf(em, __shfl_xor(em, 8));                                    \
        em = fmaxf(em, __shfl_xor(em, 16));                                   \
        em = fmaxf(em, __shfl_xor(em, 32));                                   \
        float mn = fmaxf(m, em);                                              \
        float alpha = __expf(m - mn);                                         \
        s *= alpha; acc *= alpha;                                             \
        _Pragma("unroll")                                                     \
        for (int i = 0; i < 8; ++i) {                                         \
            float pe = __expf(sc[i] - mn);                                    \
            s += pe;                                                          \
            acc = fmaf(pe, vvv[i], acc);                                      \
        }                                                                     \
        m = mn;                                                               \
    }

__global__ __launch_bounds__(256) void agg_kernel(
    const float* __restrict__ Q, const float* __restrict__ KV,
    const int* __restrict__ start, const int* __restrict__ deg,
    const int* __restrict__ elist,
    const float* __restrict__ Wo, const float* __restrict__ bo,
    float* __restrict__ out)
{
    __shared__ float wo[64 * 64];
    int tid = threadIdx.x;
    int lane = tid & 63;

    // --- T14 async-stage: issue Wo/bo loads NOW; consumed after main loop ---
    const float4* W4 = (const float4*)Wo;
    float4 wr0 = W4[tid];
    float4 wr1 = W4[tid + 256];
    float4 wr2 = W4[tid + 512];
    float4 wr3 = W4[tid + 768];          // 1024 float4 = 4096 floats total
    float bov = bo[lane];

    int n = blockIdx.x * 4 + (tid >> 6);     // grid 25000 -> n < 100000 exact
    int d = deg[n];
    int st = start[n];
    float qv = Q[n * 64 + lane];

    const float inv_scale = 0.35355339059327373f;  // 1/sqrt(8)
    float m = -INFINITY;
    float s = 0.f, acc = 0.f;

    for (int blk = 0; blk < d; blk += 64) {
        int cnt = d - blk; if (cnt > 64) cnt = 64;
        int ce = elist[st + blk + (lane < cnt ? lane : 0)];
        int j0 = 0;
        for (; j0 + 8 <= cnt; j0 += 8) CLEAN_BATCH
        if (j0 < cnt) AGG_BATCH(cnt)
    }
    float aggv = acc / (s + 1e-8f);

    // --- stage-write + barrier + fused output projection ---
    float4* wo4 = (float4*)wo;
    wo4[tid]       = wr0;
    wo4[tid + 256] = wr1;
    wo4[tid + 512] = wr2;
    wo4[tid + 768] = wr3;
    __syncthreads();

    float o = bov;
    #pragma unroll
    for (int k = 0; k < 64; ++k) {
        float ak = __shfl(aggv, k);
        o = fmaf(ak, wo[k * 64 + lane], o);
    }
    out[n * 64 + lane] = o;
}

extern "C" void kernel_launch(void* const* d_in, const int* in_sizes, int n_in,
                              void* d_out, int out_size, void* d_ws, size_t ws_size,
                              hipStream_t stream)
{
    const float* x  = (const float*)d_in[0];
    const int*   ei = (const int*)  d_in[1];   // [2*E] flattened: row then col
    const float* Wq = (const float*)d_in[2];
    const float* bq = (const float*)d_in[3];
    const float* Wk = (const float*)d_in[4];
    const float* bk = (const float*)d_in[5];
    const float* Wv = (const float*)d_in[6];
    const float* bv = (const float*)d_in[7];
    const float* Wo = (const float*)d_in[8];
    const float* bo = (const float*)d_in[9];
    float* out = (float*)d_out;

    float* Q  = (float*)d_ws;                            // N*64
    float* KV = Q + (size_t)N_NODES * 64;                // N*128 interleaved
    int* deg    = (int*)(KV + (size_t)N_NODES * 128);
    int* start  = deg + N_NODES;
    int* cursor = start + N_NODES;                       // NBUCKETS ints
    unsigned int* pairs = (unsigned int*)(cursor + 512); // NBUCKETS*BCAP (elist aliases)

    qkv_kernel<<<3125, 256, 0, stream>>>(x, Wq, bq, Wk, bk, Wv, bv, Q, KV, cursor);
    bucket_scatter_kernel<<<(N_EDGES / 4 + 511) / 512, 256, 0, stream>>>(ei, cursor, pairs);
    csr_build_kernel<<<NBUCKETS, 256, 0, stream>>>(pairs, cursor, deg, start);
    agg_kernel<<<25000, 256, 0, stream>>>(Q, KV, start, deg, (const int*)pairs, Wo, bo, out);
}